// Round 4
// baseline (441.476 us; speedup 1.0000x reference)
//
#include <hip/hip_runtime.h>
#include <hip/hip_bf16.h>

using bf16 = __hip_bfloat16;
typedef __attribute__((ext_vector_type(8))) short short8;
typedef __attribute__((ext_vector_type(4))) float f32x4;

#define DEVI static __device__ __forceinline__

DEVI short8 ld8(const void* p) { return *(const short8*)p; }
DEVI void st8(void* p, short8 v) { *(short8*)p = v; }

DEVI f32x4 mfma16(short8 a, short8 b, f32x4 c) {
  return __builtin_amdgcn_mfma_f32_16x16x32_bf16(a, b, c, 0, 0, 0);
}

// ---------------- input dtype detector -----------------------------------
// bf16 N(0,1) data: exponent field clusters ~[113,130]. f32 buffer read as
// u16: low halves have ~uniform exponent bits -> many outliers.
__global__ void detect_k(const void* __restrict__ qsrc, int* __restrict__ flag) {
  if (threadIdx.x == 0 && blockIdx.x == 0) {
    const unsigned short* u = (const unsigned short*)qsrc;
    int c = 0;
    for (int i = 0; i < 256; ++i) {
      int e = (u[i] >> 7) & 0xFF;
      if (e > 140 || e < 90) ++c;
    }
    *flag = (c >= 16) ? 1 : 0;   // 1 => f32 inputs
  }
}

// ---------------- normalize an input to bf16 ------------------------------
__global__ void convert_k(const void* __restrict__ src, bf16* __restrict__ dst,
                          int n, const int* __restrict__ flag) {
  int f = *flag;
  int i0 = (blockIdx.x * blockDim.x + threadIdx.x) * 8;
  int stride = gridDim.x * blockDim.x * 8;
  if (f) {
    const float* s = (const float*)src;
    for (int i = i0; i < n; i += stride) {
      bf16 tmp[8];
#pragma unroll
      for (int j = 0; j < 8; ++j) tmp[j] = __float2bfloat16(s[i + j]);
      st8(dst + i, *(short8*)tmp);
    }
  } else {
    const bf16* s = (const bf16*)src;
    for (int i = i0; i < n; i += stride) st8(dst + i, ld8(s + i));
  }
}

// ---------------- normalize the 5 bias vectors ----------------------------
__global__ void convert5_k(const void* b0, const void* b1, const void* b2,
                           const void* b3, const void* b4,
                           bf16* __restrict__ dst, const int* __restrict__ flag) {
  int f = *flag;
  const void* srcs[5] = {b0, b1, b2, b3, b4};
  const int sz[5] = {512, 512, 512, 2048, 2048};
  const int off[5] = {0, 512, 1024, 1536, 3584};
  for (int j = 0; j < 5; ++j)
    for (int i = threadIdx.x; i < sz[j]; i += blockDim.x)
      dst[off[j] + i] = f ? __float2bfloat16(((const float*)srcs[j])[i])
                          : ((const bf16*)srcs[j])[i];
}

// ------------- transpose+convert: src[z][R][C] -> dst[z][C][R] bf16 -------
__global__ void transpose_cvt_k(const void* __restrict__ src, bf16* __restrict__ dst,
                                int R, int C, const int* __restrict__ flag) {
  int f = *flag;
  __shared__ bf16 t[32][33];
  size_t base = (size_t)blockIdx.z * R * C;
  int c0 = blockIdx.x * 32, r0 = blockIdx.y * 32;
  int tx = threadIdx.x, ty = threadIdx.y;
  size_t si = base + (size_t)(r0 + ty) * C + (c0 + tx);
  t[ty][tx] = f ? __float2bfloat16(((const float*)src)[si]) : ((const bf16*)src)[si];
  __syncthreads();
  dst[base + (size_t)(c0 + ty) * R + (r0 + tx)] = t[tx][ty];
}

// ---------------- 128x128 GEMM core: C += A[128,K] * Bt[128,K]^T ----------
// Reg-staged global->LDS (NaN bisect: no global_load_lds this round).
DEVI void gemm128(const bf16* A, const bf16* Bt, int lda, int ldb, int K,
                  bf16* ldsA, bf16* ldsB, f32x4 (&acc)[4][4]) {
  const int t = threadIdx.x, w = t >> 6, lane = t & 63;
  const int wm = (w >> 1) * 64, wn = (w & 1) * 64;
  const int r = lane & 15, kb = (lane >> 4) * 8;
  const int flat0 = t * 16, flat1 = 4096 + t * 16;  // byte offsets in 8KB tile
  const int row0 = flat0 >> 6, cb0 = flat0 & 63;
  const int row1 = flat1 >> 6, cb1 = flat1 & 63;
  for (int k0 = 0; k0 < K; k0 += 32) {
    short8 a0 = ld8((const char*)A + (size_t)row0 * lda * 2 + (size_t)k0 * 2 + cb0);
    short8 a1 = ld8((const char*)A + (size_t)row1 * lda * 2 + (size_t)k0 * 2 + cb1);
    short8 b0 = ld8((const char*)Bt + (size_t)row0 * ldb * 2 + (size_t)k0 * 2 + cb0);
    short8 b1 = ld8((const char*)Bt + (size_t)row1 * ldb * 2 + (size_t)k0 * 2 + cb1);
    __syncthreads();
    st8((char*)ldsA + flat0, a0);
    st8((char*)ldsA + flat1, a1);
    st8((char*)ldsB + flat0, b0);
    st8((char*)ldsB + flat1, b1);
    __syncthreads();
    short8 af[4], bfv[4];
#pragma unroll
    for (int mi = 0; mi < 4; ++mi)
      af[mi] = ld8(ldsA + (wm + mi * 16 + r) * 32 + kb);
#pragma unroll
    for (int ni = 0; ni < 4; ++ni)
      bfv[ni] = ld8(ldsB + (wn + ni * 16 + r) * 32 + kb);
#pragma unroll
    for (int mi = 0; mi < 4; ++mi)
#pragma unroll
      for (int ni = 0; ni < 4; ++ni)
        acc[mi][ni] = mfma16(af[mi], bfv[ni], acc[mi][ni]);
  }
}

// ---------------- fused QKV projection -----------------------------------
__global__ __launch_bounds__(256) void qkv_k(
    const bf16* __restrict__ q, const bf16* __restrict__ k, const bf16* __restrict__ v,
    const bf16* __restrict__ WT, const bf16* __restrict__ biasN,
    bf16* __restrict__ Q0, bf16* __restrict__ Kb, bf16* __restrict__ VTb) {
  __shared__ bf16 ldsA[128 * 32];
  __shared__ bf16 ldsB[128 * 32];
  int m0 = blockIdx.x * 128;
  int bc = blockIdx.y, sel = bc >> 2, n0 = (bc & 3) * 128;
  const bf16* A = sel == 0 ? q : sel == 1 ? k : v;
  const bf16* bias = biasN + sel * 512;
  const bf16* Bt = WT + (size_t)sel * 512 * 2048 + (size_t)n0 * 2048;
  f32x4 acc[4][4];
  f32x4 z = {0.f, 0.f, 0.f, 0.f};
#pragma unroll
  for (int mi = 0; mi < 4; ++mi)
#pragma unroll
    for (int ni = 0; ni < 4; ++ni) acc[mi][ni] = z;
  gemm128(A + (size_t)m0 * 2048, Bt, 2048, 2048, 2048, ldsA, ldsB, acc);
  const int t = threadIdx.x, w = t >> 6, lane = t & 63;
  const int wm = (w >> 1) * 64, wn = (w & 1) * 64;
#pragma unroll
  for (int mi = 0; mi < 4; ++mi)
#pragma unroll
    for (int ni = 0; ni < 4; ++ni)
#pragma unroll
      for (int i = 0; i < 4; ++i) {
        int row = m0 + wm + mi * 16 + ((lane >> 4) * 4 + i);
        int ch = n0 + wn + ni * 16 + (lane & 15);
        float val = acc[mi][ni][i] + __bfloat162float(bias[ch]);
        bf16 o = __float2bfloat16(val);
        if (sel == 0)      Q0[(size_t)row * 512 + ch] = o;
        else if (sel == 1) Kb[((size_t)(ch >> 6) * 2048 + row) * 64 + (ch & 63)] = o;
        else               VTb[((size_t)(ch >> 6) * 64 + (ch & 63)) * 2048 + row] = o;
      }
}

// ---------------- per-kv-head compound transform (K=64 GEMM) --------------
__global__ __launch_bounds__(256) void gtrans_k(
    const bf16* __restrict__ Q0, const bf16* __restrict__ WGT,
    const bf16* __restrict__ bGN, bf16* __restrict__ QG) {
  __shared__ bf16 Wlds[256 * 64];  // [e][d]
  __shared__ bf16 Qlds[64 * 64];   // [n][d]
  int n0 = blockIdx.x * 64, h = blockIdx.y;
  int t = threadIdx.x, w = t >> 6, lane = t & 63;
  const char* wsrc = (const char*)(WGT + (size_t)h * 256 * 64);
  short8 wreg[8], qreg[2];
#pragma unroll
  for (int it = 0; it < 8; ++it)
    wreg[it] = ld8(wsrc + it * 4096 + t * 16);
#pragma unroll
  for (int it = 0; it < 2; ++it) {
    int flat = it * 4096 + t * 16;
    int row = flat >> 7, cb = flat & 127;
    qreg[it] = ld8((const char*)Q0 + (size_t)(n0 + row) * 1024 + h * 128 + cb);
  }
#pragma unroll
  for (int it = 0; it < 8; ++it)
    st8((char*)Wlds + it * 4096 + t * 16, wreg[it]);
#pragma unroll
  for (int it = 0; it < 2; ++it)
    st8((char*)Qlds + it * 4096 + t * 16, qreg[it]);
  __syncthreads();
  int r = lane & 15, kb = (lane >> 4) * 8;
  short8 af0 = ld8(Qlds + (w * 16 + r) * 64 + kb);
  short8 af1 = ld8(Qlds + (w * 16 + r) * 64 + 32 + kb);
#pragma unroll
  for (int ni = 0; ni < 16; ++ni) {
    f32x4 a = {0.f, 0.f, 0.f, 0.f};
    a = mfma16(af0, ld8(Wlds + (ni * 16 + r) * 64 + kb), a);
    a = mfma16(af1, ld8(Wlds + (ni * 16 + r) * 64 + 32 + kb), a);
    int e = ni * 16 + r;
    int g = e >> 6, d = e & 63;
    float bias = __bfloat162float(bGN[h * 256 + e]);
#pragma unroll
    for (int i = 0; i < 4; ++i) {
      int row = n0 + w * 16 + (lane >> 4) * 4 + i;
      QG[((size_t)(g * 8 + h) * 2048 + row) * 64 + d] = __float2bfloat16(a[i] + bias);
    }
  }
}

// ---------------- flash attention (causal, logits = S*8) ------------------
__global__ __launch_bounds__(256) void attn_k(
    const bf16* __restrict__ QG, const bf16* __restrict__ Kb,
    const bf16* __restrict__ VTb, bf16* __restrict__ AO) {
  __shared__ bf16 Klds[32 * 64];  // [s][d]
  __shared__ bf16 Vlds[64 * 32];  // [d][s]
  __shared__ bf16 Plds[64 * 32];  // [qrow][s], per-wave 16-row slices
  int q0 = blockIdx.x * 64;
  int hh = blockIdx.y, g = hh >> 3, h = hh & 7;
  int t = threadIdx.x, w = t >> 6, lane = t & 63;
  int r = lane & 15, hi = lane >> 4, kb = hi * 8;
  const bf16* Qh = QG + (size_t)hh * 2048 * 64;
  const bf16* Kh = Kb + (size_t)h * 2048 * 64;
  const bf16* Vh = VTb + (size_t)h * 64 * 2048;

  short8 qf[2];
  {
    const bf16* qp = Qh + (size_t)(q0 + w * 16 + r) * 64 + kb;
    qf[0] = ld8(qp);
    qf[1] = ld8(qp + 32);
  }
  f32x4 zv = {0.f, 0.f, 0.f, 0.f};
  f32x4 acc_o[4];
  float m_run[4], l_run[4];
#pragma unroll
  for (int i = 0; i < 4; ++i) { m_run[i] = -1e30f; l_run[i] = 0.f; }
#pragma unroll
  for (int di = 0; di < 4; ++di) acc_o[di] = zv;

  for (int s0 = 0; s0 < q0 + 64; s0 += 32) {
    short8 kreg = ld8((const char*)Kh + (size_t)s0 * 128 + t * 16);
    short8 vreg = ld8((const char*)Vh + (size_t)(t >> 2) * 4096 + (size_t)s0 * 2 + (t & 3) * 16);
    __syncthreads();
    st8((char*)Klds + t * 16, kreg);
    st8((char*)Vlds + t * 16, vreg);
    __syncthreads();

    f32x4 sa[2];
#pragma unroll
    for (int ni = 0; ni < 2; ++ni) {
      sa[ni] = zv;
      short8 kf0 = ld8(Klds + (ni * 16 + r) * 64 + kb);
      short8 kf1 = ld8(Klds + (ni * 16 + r) * 64 + 32 + kb);
      sa[ni] = mfma16(qf[0], kf0, sa[ni]);
      sa[ni] = mfma16(qf[1], kf1, sa[ni]);
    }
#pragma unroll
    for (int ni = 0; ni < 2; ++ni)
#pragma unroll
      for (int i = 0; i < 4; ++i) {
        int srow = s0 + ni * 16 + r;
        int qrow = q0 + w * 16 + hi * 4 + i;
        float vv = sa[ni][i] * 8.0f;
        sa[ni][i] = (srow <= qrow) ? vv : -1e30f;
      }
#pragma unroll
    for (int i = 0; i < 4; ++i) {
      float mx = fmaxf(sa[0][i], sa[1][i]);
#pragma unroll
      for (int d = 1; d < 16; d <<= 1) mx = fmaxf(mx, __shfl_xor(mx, d));
      float mnew = fmaxf(m_run[i], mx);
      float alpha = __expf(m_run[i] - mnew);
      m_run[i] = mnew;
      float p0 = __expf(sa[0][i] - mnew);
      float p1 = __expf(sa[1][i] - mnew);
      int prow = w * 16 + hi * 4 + i;
      Plds[prow * 32 + r] = __float2bfloat16(p0);
      Plds[prow * 32 + 16 + r] = __float2bfloat16(p1);
      float rs = p0 + p1;
#pragma unroll
      for (int d = 1; d < 16; d <<= 1) rs += __shfl_xor(rs, d);
      l_run[i] = l_run[i] * alpha + rs;
      acc_o[0][i] *= alpha; acc_o[1][i] *= alpha;
      acc_o[2][i] *= alpha; acc_o[3][i] *= alpha;
    }
    short8 pf = ld8(Plds + (w * 16 + r) * 32 + kb);
#pragma unroll
    for (int di = 0; di < 4; ++di) {
      short8 vf = ld8(Vlds + (di * 16 + r) * 32 + kb);
      acc_o[di] = mfma16(pf, vf, acc_o[di]);
    }
  }
#pragma unroll
  for (int di = 0; di < 4; ++di)
#pragma unroll
    for (int i = 0; i < 4; ++i) {
      int row = q0 + w * 16 + hi * 4 + i;
      int ch = h * 256 + g * 64 + di * 16 + r;
      AO[(size_t)row * 2048 + ch] = __float2bfloat16(acc_o[di][i] / l_run[i]);
    }
}

// ---------------- output projection (dtype-flexible store) ----------------
__global__ __launch_bounds__(256) void outproj_k(
    const bf16* __restrict__ AO, const bf16* __restrict__ WfcT,
    const bf16* __restrict__ bfcN, void* __restrict__ outv,
    const int* __restrict__ flag) {
  __shared__ bf16 ldsA[128 * 32];
  __shared__ bf16 ldsB[128 * 32];
  int f = *flag;
  int m0 = blockIdx.x * 128, n0 = blockIdx.y * 128;
  f32x4 acc[4][4];
  f32x4 z = {0.f, 0.f, 0.f, 0.f};
#pragma unroll
  for (int mi = 0; mi < 4; ++mi)
#pragma unroll
    for (int ni = 0; ni < 4; ++ni) acc[mi][ni] = z;
  gemm128(AO + (size_t)m0 * 2048, WfcT + (size_t)n0 * 2048, 2048, 2048, 2048,
          ldsA, ldsB, acc);
  const int t = threadIdx.x, w = t >> 6, lane = t & 63;
  const int wm = (w >> 1) * 64, wn = (w & 1) * 64;
#pragma unroll
  for (int mi = 0; mi < 4; ++mi)
#pragma unroll
    for (int ni = 0; ni < 4; ++ni)
#pragma unroll
      for (int i = 0; i < 4; ++i) {
        int row = m0 + wm + mi * 16 + ((lane >> 4) * 4 + i);
        int ch = n0 + wn + ni * 16 + (lane & 15);
        float val = acc[mi][ni][i] + __bfloat162float(bfcN[ch]);
        size_t idx = (size_t)row * 2048 + ch;
        if (f) ((float*)outv)[idx] = val;
        else   ((bf16*)outv)[idx] = __float2bfloat16(val);
      }
}

extern "C" void kernel_launch(void* const* d_in, const int* in_sizes, int n_in,
                              void* d_out, int out_size, void* d_ws, size_t ws_size,
                              hipStream_t stream) {
  const void* q   = d_in[0];
  const void* k   = d_in[1];
  const void* v   = d_in[2];
  const void* Wq  = d_in[3];
  const void* bq  = d_in[4];
  const void* Wk  = d_in[5];
  const void* bk  = d_in[6];
  const void* Wv  = d_in[7];
  const void* bv  = d_in[8];
  const void* WG  = d_in[9];
  const void* bG  = d_in[10];
  const void* Wfc = d_in[11];
  const void* bfc = d_in[12];

  bf16* ws = (bf16*)d_ws;
  int* flag = (int*)d_ws;                                    // elems [0,32)
  bf16* biasN = ws + 32;                                     // 5632 elems
  bf16* WT    = ws + 6144;          // 3*512*2048
  bf16* WGT   = ws + 3151872;       // 8*256*64
  bf16* Q0    = ws + 3282944;       // 2048*512
  bf16* Kb    = ws + 4331520;       // 8*2048*64
  bf16* VTb   = ws + 5380096;       // 8*64*2048
  bf16* R1    = ws + 6428672;       // 4M: qn, then QG
  bf16* R2    = ws + 10622976;      // 4M: kn, then AO
  bf16* R3    = ws + 14817280;      // 4M: vn, then WfcT
  bf16* qn = R1; bf16* QG = R1;
  bf16* kn = R2; bf16* AO = R2;
  bf16* vn = R3; bf16* WfcT = R3;
  bf16* bGN = biasN + 1536, *bfcN = biasN + 3584;

  detect_k<<<1, 64, 0, stream>>>(q, flag);
  convert_k<<<2048, 256, 0, stream>>>(q, qn, 4194304, flag);
  convert_k<<<2048, 256, 0, stream>>>(k, kn, 4194304, flag);
  convert_k<<<2048, 256, 0, stream>>>(v, vn, 4194304, flag);
  convert5_k<<<1, 256, 0, stream>>>(bq, bk, bv, bG, bfc, biasN, flag);

  dim3 b32(32, 32, 1);
  transpose_cvt_k<<<dim3(16, 64, 1), b32, 0, stream>>>(Wq, WT, 2048, 512, flag);
  transpose_cvt_k<<<dim3(16, 64, 1), b32, 0, stream>>>(Wk, WT + (size_t)512 * 2048, 2048, 512, flag);
  transpose_cvt_k<<<dim3(16, 64, 1), b32, 0, stream>>>(Wv, WT + (size_t)2 * 512 * 2048, 2048, 512, flag);
  transpose_cvt_k<<<dim3(8, 2, 8),   b32, 0, stream>>>(WG, WGT, 64, 256, flag);

  qkv_k<<<dim3(16, 12, 1), 256, 0, stream>>>(qn, kn, vn, WT, biasN, Q0, Kb, VTb);
  gtrans_k<<<dim3(32, 8, 1), 256, 0, stream>>>(Q0, WGT, bGN, QG);
  attn_k<<<dim3(32, 32, 1), 256, 0, stream>>>(QG, Kb, VTb, AO);
  // Wfc transpose AFTER attn (R3 aliased: vn dead, WfcT needed only by outproj)
  transpose_cvt_k<<<dim3(64, 64, 1), b32, 0, stream>>>(Wfc, WfcT, 2048, 2048, flag);
  outproj_k<<<dim3(16, 16, 1), 256, 0, stream>>>(AO, WfcT, bfcN, d_out, flag);
}

// Round 6
// 329.511 us; speedup vs baseline: 1.3398x; 1.3398x over previous
//
#include <hip/hip_runtime.h>
#include <hip/hip_bf16.h>

using bf16 = __hip_bfloat16;
typedef __attribute__((ext_vector_type(8))) short short8;
typedef __attribute__((ext_vector_type(4))) float f32x4;
typedef __attribute__((ext_vector_type(16))) float f32x16;
typedef __attribute__((ext_vector_type(4))) unsigned u32x4;
typedef __attribute__((ext_vector_type(4))) short s16x4;

#define DEVI static __device__ __forceinline__

DEVI short8 ld8(const void* p) { return *(const short8*)p; }
DEVI void st8(void* p, short8 v) { *(short8*)p = v; }

DEVI f32x4 mfma16(short8 a, short8 b, f32x4 c) {
  return __builtin_amdgcn_mfma_f32_16x16x32_bf16(a, b, c, 0, 0, 0);
}
DEVI f32x16 mfma32(short8 a, short8 b, f32x16 c) {
  return __builtin_amdgcn_mfma_f32_32x32x16_bf16(a, b, c, 0, 0, 0);
}
DEVI unsigned pk2(float a, float b) {
  unsigned short ua = __builtin_bit_cast(unsigned short, __float2bfloat16(a));
  unsigned short ub = __builtin_bit_cast(unsigned short, __float2bfloat16(b));
  return (unsigned)ua | ((unsigned)ub << 16);
}
// swizzled LDS byte offset for [row][128B] tiles
DEVI int swz(int row, int colb) { return row * 128 + (colb ^ ((row & 7) << 4)); }

// ---------------- input dtype detector -----------------------------------
__global__ void detect_k(const void* __restrict__ qsrc, int* __restrict__ flag) {
  if (threadIdx.x == 0 && blockIdx.x == 0) {
    const unsigned short* u = (const unsigned short*)qsrc;
    int c = 0;
    for (int i = 0; i < 256; ++i) {
      int e = (u[i] >> 7) & 0xFF;
      if (e > 140 || e < 90) ++c;
    }
    *flag = (c >= 16) ? 1 : 0;  // 1 => f32 inputs
  }
}

// ---------------- normalize q/k/v to bf16 (fused, z selects) --------------
__global__ void convert3_k(const void* __restrict__ s0, const void* __restrict__ s1,
                           const void* __restrict__ s2, bf16* __restrict__ d0,
                           bf16* __restrict__ d1, bf16* __restrict__ d2, int n,
                           const int* __restrict__ flag) {
  int z = blockIdx.z;
  const void* src = z == 0 ? s0 : z == 1 ? s1 : s2;
  bf16* dst = z == 0 ? d0 : z == 1 ? d1 : d2;
  int f = *flag;
  int i0 = (blockIdx.x * blockDim.x + threadIdx.x) * 8;
  int stride = gridDim.x * blockDim.x * 8;
  if (f) {
    const float* s = (const float*)src;
    for (int i = i0; i < n; i += stride) {
      bf16 tmp[8];
#pragma unroll
      for (int j = 0; j < 8; ++j) tmp[j] = __float2bfloat16(s[i + j]);
      st8(dst + i, *(short8*)tmp);
    }
  } else {
    const bf16* s = (const bf16*)src;
    for (int i = i0; i < n; i += stride) st8(dst + i, ld8(s + i));
  }
}

// ---------------- normalize the 5 bias vectors ----------------------------
__global__ void convert5_k(const void* b0, const void* b1, const void* b2,
                           const void* b3, const void* b4,
                           bf16* __restrict__ dst, const int* __restrict__ flag) {
  int f = *flag;
  const void* srcs[5] = {b0, b1, b2, b3, b4};
  const int sz[5] = {512, 512, 512, 2048, 2048};
  const int off[5] = {0, 512, 1024, 1536, 3584};
  for (int j = 0; j < 5; ++j)
    for (int i = threadIdx.x; i < sz[j]; i += blockDim.x)
      dst[off[j] + i] = f ? __float2bfloat16(((const float*)srcs[j])[i])
                          : ((const bf16*)srcs[j])[i];
}

// ------------- transpose+convert: src[z][R][C] -> dst[z][C][R] bf16 -------
__global__ void transpose_cvt_k(const void* __restrict__ src, bf16* __restrict__ dst,
                                int R, int C, const int* __restrict__ flag) {
  int f = *flag;
  __shared__ bf16 t[32][33];
  size_t base = (size_t)blockIdx.z * R * C;
  int c0 = blockIdx.x * 32, r0 = blockIdx.y * 32;
  int tx = threadIdx.x, ty = threadIdx.y;
  size_t si = base + (size_t)(r0 + ty) * C + (c0 + tx);
  t[ty][tx] = f ? __float2bfloat16(((const float*)src)[si]) : ((const bf16*)src)[si];
  __syncthreads();
  dst[base + (size_t)(c0 + ty) * R + (r0 + tx)] = t[tx][ty];
}

// ------------- fused Wq/Wk/Wv transpose (z = which weight) ----------------
__global__ void transpose_w3_k(const void* __restrict__ w0, const void* __restrict__ w1,
                               const void* __restrict__ w2, bf16* __restrict__ dst,
                               const int* __restrict__ flag) {
  int f = *flag;
  int sel = blockIdx.z;
  const void* src = sel == 0 ? w0 : sel == 1 ? w1 : w2;
  bf16* d = dst + (size_t)sel * 512 * 2048;
  __shared__ bf16 t[32][33];
  int c0 = blockIdx.x * 32, r0 = blockIdx.y * 32;
  int tx = threadIdx.x, ty = threadIdx.y;
  size_t si = (size_t)(r0 + ty) * 512 + (c0 + tx);
  t[ty][tx] = f ? __float2bfloat16(((const float*)src)[si]) : ((const bf16*)src)[si];
  __syncthreads();
  d[(size_t)(c0 + ty) * 2048 + (r0 + tx)] = t[tx][ty];
}

// ---------------- 128x128 GEMM core (reg-staged, verified) ----------------
DEVI void gemm128(const bf16* A, const bf16* Bt, int lda, int ldb, int K,
                  bf16* ldsA, bf16* ldsB, f32x4 (&acc)[4][4]) {
  const int t = threadIdx.x, w = t >> 6, lane = t & 63;
  const int wm = (w >> 1) * 64, wn = (w & 1) * 64;
  const int r = lane & 15, kb = (lane >> 4) * 8;
  const int flat0 = t * 16, flat1 = 4096 + t * 16;
  const int row0 = flat0 >> 6, cb0 = flat0 & 63;
  const int row1 = flat1 >> 6, cb1 = flat1 & 63;
  for (int k0 = 0; k0 < K; k0 += 32) {
    short8 a0 = ld8((const char*)A + (size_t)row0 * lda * 2 + (size_t)k0 * 2 + cb0);
    short8 a1 = ld8((const char*)A + (size_t)row1 * lda * 2 + (size_t)k0 * 2 + cb1);
    short8 b0 = ld8((const char*)Bt + (size_t)row0 * ldb * 2 + (size_t)k0 * 2 + cb0);
    short8 b1 = ld8((const char*)Bt + (size_t)row1 * ldb * 2 + (size_t)k0 * 2 + cb1);
    __syncthreads();
    st8((char*)ldsA + flat0, a0);
    st8((char*)ldsA + flat1, a1);
    st8((char*)ldsB + flat0, b0);
    st8((char*)ldsB + flat1, b1);
    __syncthreads();
    short8 af[4], bfv[4];
#pragma unroll
    for (int mi = 0; mi < 4; ++mi)
      af[mi] = ld8(ldsA + (wm + mi * 16 + r) * 32 + kb);
#pragma unroll
    for (int ni = 0; ni < 4; ++ni)
      bfv[ni] = ld8(ldsB + (wn + ni * 16 + r) * 32 + kb);
#pragma unroll
    for (int mi = 0; mi < 4; ++mi)
#pragma unroll
      for (int ni = 0; ni < 4; ++ni)
        acc[mi][ni] = mfma16(af[mi], bfv[ni], acc[mi][ni]);
  }
}

// ---------------- fused QKV projection -----------------------------------
__global__ __launch_bounds__(256) void qkv_k(
    const bf16* __restrict__ q, const bf16* __restrict__ k, const bf16* __restrict__ v,
    const bf16* __restrict__ WT, const bf16* __restrict__ biasN,
    bf16* __restrict__ Q0, bf16* __restrict__ Kb, bf16* __restrict__ VTb) {
  __shared__ bf16 ldsA[128 * 32];
  __shared__ bf16 ldsB[128 * 32];
  int m0 = blockIdx.x * 128;
  int bc = blockIdx.y, sel = bc >> 2, n0 = (bc & 3) * 128;
  const bf16* A = sel == 0 ? q : sel == 1 ? k : v;
  const bf16* bias = biasN + sel * 512;
  const bf16* Bt = WT + (size_t)sel * 512 * 2048 + (size_t)n0 * 2048;
  f32x4 acc[4][4];
  f32x4 z = {0.f, 0.f, 0.f, 0.f};
#pragma unroll
  for (int mi = 0; mi < 4; ++mi)
#pragma unroll
    for (int ni = 0; ni < 4; ++ni) acc[mi][ni] = z;
  gemm128(A + (size_t)m0 * 2048, Bt, 2048, 2048, 2048, ldsA, ldsB, acc);
  const int t = threadIdx.x, w = t >> 6, lane = t & 63;
  const int wm = (w >> 1) * 64, wn = (w & 1) * 64;
#pragma unroll
  for (int mi = 0; mi < 4; ++mi)
#pragma unroll
    for (int ni = 0; ni < 4; ++ni)
#pragma unroll
      for (int i = 0; i < 4; ++i) {
        int row = m0 + wm + mi * 16 + ((lane >> 4) * 4 + i);
        int ch = n0 + wn + ni * 16 + (lane & 15);
        float val = acc[mi][ni][i] + __bfloat162float(bias[ch]);
        bf16 o = __float2bfloat16(val);
        if (sel == 0)      Q0[(size_t)row * 512 + ch] = o;
        else if (sel == 1) Kb[((size_t)(ch >> 6) * 2048 + row) * 64 + (ch & 63)] = o;
        else               VTb[((size_t)(ch >> 6) * 64 + (ch & 63)) * 2048 + row] = o;
      }
}

// ---------------- per-kv-head compound transform (K=64 GEMM) --------------
// NOTE: output pre-scaled by 8 (softmax logit scale), exact in bf16.
__global__ __launch_bounds__(256) void gtrans_k(
    const bf16* __restrict__ Q0, const bf16* __restrict__ WGT,
    const bf16* __restrict__ bGN, bf16* __restrict__ QG) {
  __shared__ bf16 Wlds[256 * 64];
  __shared__ bf16 Qlds[64 * 64];
  int n0 = blockIdx.x * 64, h = blockIdx.y;
  int t = threadIdx.x, w = t >> 6, lane = t & 63;
  const char* wsrc = (const char*)(WGT + (size_t)h * 256 * 64);
  short8 wreg[8], qreg[2];
#pragma unroll
  for (int it = 0; it < 8; ++it)
    wreg[it] = ld8(wsrc + it * 4096 + t * 16);
#pragma unroll
  for (int it = 0; it < 2; ++it) {
    int flat = it * 4096 + t * 16;
    int row = flat >> 7, cb = flat & 127;
    qreg[it] = ld8((const char*)Q0 + (size_t)(n0 + row) * 1024 + h * 128 + cb);
  }
#pragma unroll
  for (int it = 0; it < 8; ++it)
    st8((char*)Wlds + it * 4096 + t * 16, wreg[it]);
#pragma unroll
  for (int it = 0; it < 2; ++it)
    st8((char*)Qlds + it * 4096 + t * 16, qreg[it]);
  __syncthreads();
  int r = lane & 15, kb = (lane >> 4) * 8;
  short8 af0 = ld8(Qlds + (w * 16 + r) * 64 + kb);
  short8 af1 = ld8(Qlds + (w * 16 + r) * 64 + 32 + kb);
#pragma unroll
  for (int ni = 0; ni < 16; ++ni) {
    f32x4 a = {0.f, 0.f, 0.f, 0.f};
    a = mfma16(af0, ld8(Wlds + (ni * 16 + r) * 64 + kb), a);
    a = mfma16(af1, ld8(Wlds + (ni * 16 + r) * 64 + 32 + kb), a);
    int e = ni * 16 + r;
    int g = e >> 6, d = e & 63;
    float bias = __bfloat162float(bGN[h * 256 + e]);
#pragma unroll
    for (int i = 0; i < 4; ++i) {
      int row = n0 + w * 16 + (lane >> 4) * 4 + i;
      QG[((size_t)(g * 8 + h) * 2048 + row) * 64 + d] =
          __float2bfloat16((a[i] + bias) * 8.0f);
    }
  }
}

// ---------------- flash attention, 32x32 swapped-operand form -------------
// grid (16 qtiles of 128 [reversed: heavy first], 32 heads); 4 waves x 32 q.
__global__ __launch_bounds__(256) void attn_k(
    const bf16* __restrict__ QG, const bf16* __restrict__ Kb,
    const bf16* __restrict__ VTb, bf16* __restrict__ AO) {
  __shared__ bf16 Klds[2][64 * 64];  // [s][d], xor-swizzled rows
  __shared__ bf16 Vlds[2][64 * 64];  // [d][s], xor-swizzled rows
  int q0 = (gridDim.x - 1 - blockIdx.x) * 128;
  int hh = blockIdx.y, g = hh >> 3, h = hh & 7;
  int t = threadIdx.x, w = t >> 6, lane = t & 63;
  int qq = lane & 31, hp = lane >> 5;
  const char* Khb = (const char*)(Kb + (size_t)h * 2048 * 64);
  const char* Vhb = (const char*)(VTb + (size_t)h * 64 * 2048);
  const bf16* Qh = QG + (size_t)hh * 2048 * 64;
  int qrow = q0 + w * 32 + qq;
  int qmin = q0 + w * 32;

  short8 qf[4];
#pragma unroll
  for (int kc = 0; kc < 4; ++kc)
    qf[kc] = ld8(Qh + (size_t)qrow * 64 + kc * 16 + hp * 8);

  int srow = t >> 3;             // 0..31
  int scolb = (t & 7) * 16;      // 0..112
  int soff = swz(srow, scolb);
  int soff2 = swz(srow + 32, scolb);

  f32x16 acc[2];
#pragma unroll
  for (int i = 0; i < 16; ++i) { acc[0][i] = 0.f; acc[1][i] = 0.f; }
  float m_run = -1e30f, l_run = 0.f;

  int nt = q0 / 64 + 2;
  {  // prologue: stage tile 0
    short8 k0 = ld8(Khb + (size_t)srow * 128 + scolb);
    short8 k1 = ld8(Khb + (size_t)(srow + 32) * 128 + scolb);
    short8 v0 = ld8(Vhb + (size_t)srow * 4096 + scolb);
    short8 v1 = ld8(Vhb + (size_t)(srow + 32) * 4096 + scolb);
    st8((char*)Klds[0] + soff, k0);
    st8((char*)Klds[0] + soff2, k1);
    st8((char*)Vlds[0] + soff, v0);
    st8((char*)Vlds[0] + soff2, v1);
  }
  for (int tt = 0; tt < nt; ++tt) {
    int cur = tt & 1;
    int s0 = tt * 64;
    __syncthreads();
    bool have_next = (tt + 1 < nt);
    short8 nk0, nk1, nv0, nv1;
    if (have_next) {
      int sn = s0 + 64;
      nk0 = ld8(Khb + (size_t)(sn + srow) * 128 + scolb);
      nk1 = ld8(Khb + (size_t)(sn + srow + 32) * 128 + scolb);
      nv0 = ld8(Vhb + (size_t)srow * 4096 + sn * 2 + scolb);
      nv1 = ld8(Vhb + (size_t)(srow + 32) * 4096 + sn * 2 + scolb);
    }
    if (s0 <= qmin + 31) {  // wave-uniform: skip fully-masked tiles
      const char* Kc = (const char*)Klds[cur];
      const char* Vc = (const char*)Vlds[cur];
      f32x16 sa0, sa1;
#pragma unroll
      for (int i = 0; i < 16; ++i) { sa0[i] = 0.f; sa1[i] = 0.f; }
#pragma unroll
      for (int kc = 0; kc < 4; ++kc) {
        short8 kf0 = ld8(Kc + swz(qq, kc * 32 + hp * 16));
        short8 kf1 = ld8(Kc + swz(32 + qq, kc * 32 + hp * 16));
        sa0 = mfma32(kf0, qf[kc], sa0);   // D[s][q]: s=rows, q=lane&31
        sa1 = mfma32(kf1, qf[kc], sa1);
      }
      if (s0 + 63 > qmin) {  // wave-uniform: mask only near diagonal
#pragma unroll
        for (int rg = 0; rg < 16; ++rg) {
          int sr = s0 + (rg & 3) + 8 * (rg >> 2) + 4 * hp;
          if (sr > qrow) sa0[rg] = -1e30f;
          if (sr + 32 > qrow) sa1[rg] = -1e30f;
        }
      }
      float tmax = sa0[0];
#pragma unroll
      for (int rg = 1; rg < 16; ++rg) tmax = fmaxf(tmax, sa0[rg]);
#pragma unroll
      for (int rg = 0; rg < 16; ++rg) tmax = fmaxf(tmax, sa1[rg]);
      tmax = fmaxf(tmax, __shfl_xor(tmax, 32));
      float mnew = fmaxf(m_run, tmax);
      float alpha = __expf(m_run - mnew);
      m_run = mnew;
      float rs = 0.f;
#pragma unroll
      for (int rg = 0; rg < 16; ++rg) { sa0[rg] = __expf(sa0[rg] - mnew); rs += sa0[rg]; }
#pragma unroll
      for (int rg = 0; rg < 16; ++rg) { sa1[rg] = __expf(sa1[rg] - mnew); rs += sa1[rg]; }
      rs += __shfl_xor(rs, 32);
      l_run = l_run * alpha + rs;
#pragma unroll
      for (int i = 0; i < 16; ++i) { acc[0][i] *= alpha; acc[1][i] *= alpha; }
      unsigned wpk0[8], wpk1[8];
#pragma unroll
      for (int rp = 0; rp < 8; ++rp) {
        wpk0[rp] = pk2(sa0[2 * rp], sa0[2 * rp + 1]);
        wpk1[rp] = pk2(sa1[2 * rp], sa1[2 * rp + 1]);
      }
#pragma unroll
      for (int kc = 0; kc < 4; ++kc) {
        const unsigned* wp = (kc < 2) ? wpk0 : wpk1;
        int base = (kc & 1) * 4;
        unsigned own0 = wp[base + 0], own1 = wp[base + 1];
        unsigned own2 = wp[base + 2], own3 = wp[base + 3];
        unsigned send0 = hp ? own0 : own2;
        unsigned send1 = hp ? own1 : own3;
        unsigned r0 = (unsigned)__shfl_xor((int)send0, 32);
        unsigned r1 = (unsigned)__shfl_xor((int)send1, 32);
        u32x4 pv;
        pv[0] = hp ? r0 : own0;
        pv[1] = hp ? r1 : own1;
        pv[2] = hp ? own2 : r0;
        pv[3] = hp ? own3 : r1;
        short8 pa = __builtin_bit_cast(short8, pv);
        short8 vf0 = ld8(Vc + swz(qq, kc * 32 + hp * 16));
        short8 vf1 = ld8(Vc + swz(32 + qq, kc * 32 + hp * 16));
        acc[0] = mfma32(vf0, pa, acc[0]);  // D[d][q]: d=rows, q=lane&31
        acc[1] = mfma32(vf1, pa, acc[1]);
      }
    }
    if (have_next) {
      int nb = cur ^ 1;
      st8((char*)Klds[nb] + soff, nk0);
      st8((char*)Klds[nb] + soff2, nk1);
      st8((char*)Vlds[nb] + soff, nv0);
      st8((char*)Vlds[nb] + soff2, nv1);
    }
  }
  float rli = 1.0f / l_run;
  bf16* aob = AO + (size_t)qrow * 2048 + h * 256 + g * 64;
#pragma unroll
  for (int ds = 0; ds < 2; ++ds)
#pragma unroll
    for (int rq = 0; rq < 4; ++rq) {
      s16x4 o4;
#pragma unroll
      for (int i = 0; i < 4; ++i)
        o4[i] = __builtin_bit_cast(short, __float2bfloat16(acc[ds][rq * 4 + i] * rli));
      int d0 = ds * 32 + 8 * rq + 4 * hp;
      *(s16x4*)(aob + d0) = o4;
    }
}

// ---------------- output projection (dtype-flexible store) ----------------
__global__ __launch_bounds__(256) void outproj_k(
    const bf16* __restrict__ AO, const bf16* __restrict__ WfcT,
    const bf16* __restrict__ bfcN, void* __restrict__ outv,
    const int* __restrict__ flag) {
  __shared__ bf16 ldsA[128 * 32];
  __shared__ bf16 ldsB[128 * 32];
  int f = *flag;
  int m0 = blockIdx.x * 128, n0 = blockIdx.y * 128;
  f32x4 acc[4][4];
  f32x4 z = {0.f, 0.f, 0.f, 0.f};
#pragma unroll
  for (int mi = 0; mi < 4; ++mi)
#pragma unroll
    for (int ni = 0; ni < 4; ++ni) acc[mi][ni] = z;
  gemm128(AO + (size_t)m0 * 2048, WfcT + (size_t)n0 * 2048, 2048, 2048, 2048,
          ldsA, ldsB, acc);
  const int t = threadIdx.x, w = t >> 6, lane = t & 63;
  const int wm = (w >> 1) * 64, wn = (w & 1) * 64;
#pragma unroll
  for (int mi = 0; mi < 4; ++mi)
#pragma unroll
    for (int ni = 0; ni < 4; ++ni)
#pragma unroll
      for (int i = 0; i < 4; ++i) {
        int row = m0 + wm + mi * 16 + ((lane >> 4) * 4 + i);
        int ch = n0 + wn + ni * 16 + (lane & 15);
        float val = acc[mi][ni][i] + __bfloat162float(bfcN[ch]);
        size_t idx = (size_t)row * 2048 + ch;
        if (f) ((float*)outv)[idx] = val;
        else   ((bf16*)outv)[idx] = __float2bfloat16(val);
      }
}

extern "C" void kernel_launch(void* const* d_in, const int* in_sizes, int n_in,
                              void* d_out, int out_size, void* d_ws, size_t ws_size,
                              hipStream_t stream) {
  const void* q   = d_in[0];
  const void* k   = d_in[1];
  const void* v   = d_in[2];
  const void* Wq  = d_in[3];
  const void* bq  = d_in[4];
  const void* Wk  = d_in[5];
  const void* bk  = d_in[6];
  const void* Wv  = d_in[7];
  const void* bv  = d_in[8];
  const void* WG  = d_in[9];
  const void* bG  = d_in[10];
  const void* Wfc = d_in[11];
  const void* bfc = d_in[12];

  bf16* ws = (bf16*)d_ws;
  int* flag = (int*)d_ws;           // elems [0,32)
  bf16* biasN = ws + 32;
  bf16* WT    = ws + 6144;          // 3*512*2048
  bf16* WGT   = ws + 3151872;       // 8*256*64
  bf16* Q0    = ws + 3282944;       // 2048*512
  bf16* Kb    = ws + 4331520;       // 8*2048*64
  bf16* VTb   = ws + 5380096;       // 8*64*2048
  bf16* R1    = ws + 6428672;       // 4M: qn, then QG
  bf16* R2    = ws + 10622976;      // 4M: kn, then AO
  bf16* R3    = ws + 14817280;      // 4M: vn, then WfcT
  bf16* qn = R1; bf16* QG = R1;
  bf16* kn = R2; bf16* AO = R2;
  bf16* vn = R3; bf16* WfcT = R3;
  bf16* bGN = biasN + 1536, *bfcN = biasN + 3584;

  detect_k<<<1, 64, 0, stream>>>(q, flag);
  convert3_k<<<dim3(1024, 1, 3), 256, 0, stream>>>(q, k, v, qn, kn, vn, 4194304, flag);
  convert5_k<<<1, 256, 0, stream>>>(bq, bk, bv, bG, bfc, biasN, flag);

  dim3 b32(32, 32, 1);
  transpose_w3_k<<<dim3(16, 64, 3), b32, 0, stream>>>(Wq, Wk, Wv, WT, flag);
  transpose_cvt_k<<<dim3(8, 2, 8), b32, 0, stream>>>(WG, WGT, 64, 256, flag);

  qkv_k<<<dim3(16, 12, 1), 256, 0, stream>>>(qn, kn, vn, WT, biasN, Q0, Kb, VTb);
  gtrans_k<<<dim3(32, 8, 1), 256, 0, stream>>>(Q0, WGT, bGN, QG);
  attn_k<<<dim3(16, 32, 1), 256, 0, stream>>>(QG, Kb, VTb, AO);
  transpose_cvt_k<<<dim3(64, 64, 1), b32, 0, stream>>>(Wfc, WfcT, 2048, 2048, flag);
  outproj_k<<<dim3(16, 16, 1), 256, 0, stream>>>(AO, WfcT, bfcN, d_out, flag);
}

// Round 7
// 316.654 us; speedup vs baseline: 1.3942x; 1.0406x over previous
//
#include <hip/hip_runtime.h>
#include <hip/hip_bf16.h>

using bf16 = __hip_bfloat16;
typedef __attribute__((ext_vector_type(8))) short short8;
typedef __attribute__((ext_vector_type(4))) float f32x4;
typedef __attribute__((ext_vector_type(16))) float f32x16;
typedef __attribute__((ext_vector_type(4))) unsigned u32x4;
typedef __attribute__((ext_vector_type(4))) short s16x4;

#define DEVI static __device__ __forceinline__

DEVI short8 ld8(const void* p) { return *(const short8*)p; }
DEVI void st8(void* p, short8 v) { *(short8*)p = v; }

DEVI void async_load16(const void* g, void* lds) {
  __builtin_amdgcn_global_load_lds(
      (__attribute__((address_space(1))) void*)g,
      (__attribute__((address_space(3))) void*)lds, 16, 0, 0);
}

DEVI f32x4 mfma16(short8 a, short8 b, f32x4 c) {
  return __builtin_amdgcn_mfma_f32_16x16x32_bf16(a, b, c, 0, 0, 0);
}
DEVI f32x16 mfma32(short8 a, short8 b, f32x16 c) {
  return __builtin_amdgcn_mfma_f32_32x32x16_bf16(a, b, c, 0, 0, 0);
}
DEVI unsigned pk2(float a, float b) {
  unsigned short ua = __builtin_bit_cast(unsigned short, __float2bfloat16(a));
  unsigned short ub = __builtin_bit_cast(unsigned short, __float2bfloat16(b));
  return (unsigned)ua | ((unsigned)ub << 16);
}

// ---------------- input dtype detector -----------------------------------
__global__ void detect_k(const void* __restrict__ qsrc, int* __restrict__ flag) {
  if (threadIdx.x == 0 && blockIdx.x == 0) {
    const unsigned short* u = (const unsigned short*)qsrc;
    int c = 0;
    for (int i = 0; i < 256; ++i) {
      int e = (u[i] >> 7) & 0xFF;
      if (e > 140 || e < 90) ++c;
    }
    *flag = (c >= 16) ? 1 : 0;  // 1 => f32 inputs
  }
}

// ---------------- normalize q/k/v to bf16 (fused, z selects) --------------
__global__ void convert3_k(const void* __restrict__ s0, const void* __restrict__ s1,
                           const void* __restrict__ s2, bf16* __restrict__ d0,
                           bf16* __restrict__ d1, bf16* __restrict__ d2, int n,
                           const int* __restrict__ flag) {
  int z = blockIdx.z;
  const void* src = z == 0 ? s0 : z == 1 ? s1 : s2;
  bf16* dst = z == 0 ? d0 : z == 1 ? d1 : d2;
  int f = *flag;
  int i0 = (blockIdx.x * blockDim.x + threadIdx.x) * 8;
  int stride = gridDim.x * blockDim.x * 8;
  if (f) {
    const float* s = (const float*)src;
    for (int i = i0; i < n; i += stride) {
      bf16 tmp[8];
#pragma unroll
      for (int j = 0; j < 8; ++j) tmp[j] = __float2bfloat16(s[i + j]);
      st8(dst + i, *(short8*)tmp);
    }
  } else {
    const bf16* s = (const bf16*)src;
    for (int i = i0; i < n; i += stride) st8(dst + i, ld8(s + i));
  }
}

// ---------------- normalize the 5 bias vectors ----------------------------
__global__ void convert5_k(const void* b0, const void* b1, const void* b2,
                           const void* b3, const void* b4,
                           bf16* __restrict__ dst, const int* __restrict__ flag) {
  int f = *flag;
  const void* srcs[5] = {b0, b1, b2, b3, b4};
  const int sz[5] = {512, 512, 512, 2048, 2048};
  const int off[5] = {0, 512, 1024, 1536, 3584};
  for (int j = 0; j < 5; ++j)
    for (int i = threadIdx.x; i < sz[j]; i += blockDim.x)
      dst[off[j] + i] = f ? __float2bfloat16(((const float*)srcs[j])[i])
                          : ((const bf16*)srcs[j])[i];
}

// ------------- transpose+convert: src[z][R][C] -> dst[z][C][R] bf16 -------
__global__ void transpose_cvt_k(const void* __restrict__ src, bf16* __restrict__ dst,
                                int R, int C, const int* __restrict__ flag) {
  int f = *flag;
  __shared__ bf16 t[32][33];
  size_t base = (size_t)blockIdx.z * R * C;
  int c0 = blockIdx.x * 32, r0 = blockIdx.y * 32;
  int tx = threadIdx.x, ty = threadIdx.y;
  size_t si = base + (size_t)(r0 + ty) * C + (c0 + tx);
  t[ty][tx] = f ? __float2bfloat16(((const float*)src)[si]) : ((const bf16*)src)[si];
  __syncthreads();
  dst[base + (size_t)(c0 + ty) * R + (r0 + tx)] = t[tx][ty];
}

// ------------- fused Wq/Wk/Wv transpose (z = which weight) ----------------
__global__ void transpose_w3_k(const void* __restrict__ w0, const void* __restrict__ w1,
                               const void* __restrict__ w2, bf16* __restrict__ dst,
                               const int* __restrict__ flag) {
  int f = *flag;
  int sel = blockIdx.z;
  const void* src = sel == 0 ? w0 : sel == 1 ? w1 : w2;
  bf16* d = dst + (size_t)sel * 512 * 2048;
  __shared__ bf16 t[32][33];
  int c0 = blockIdx.x * 32, r0 = blockIdx.y * 32;
  int tx = threadIdx.x, ty = threadIdx.y;
  size_t si = (size_t)(r0 + ty) * 512 + (c0 + tx);
  t[ty][tx] = f ? __float2bfloat16(((const float*)src)[si]) : ((const bf16*)src)[si];
  __syncthreads();
  d[(size_t)(c0 + ty) * 2048 + (r0 + tx)] = t[tx][ty];
}

// ------------- 128x128 GEMM core (async global_load_lds, m97-style) -------
DEVI void gemm128(const bf16* A, const bf16* Bt, int lda, int ldb, int K,
                  bf16* ldsA, bf16* ldsB, f32x4 (&acc)[4][4]) {
  const int t = threadIdx.x, w = t >> 6, lane = t & 63;
  const int wm = (w >> 1) * 64, wn = (w & 1) * 64;
  const int r = lane & 15, kb = (lane >> 4) * 8;
  for (int k0 = 0; k0 < K; k0 += 32) {
    __syncthreads();
#pragma unroll
    for (int it = 0; it < 2; ++it) {
      int flat = it * 4096 + t * 16;     // byte offset into 8KB tile
      int row = flat >> 6, cb = flat & 63;
      async_load16((const char*)A + (size_t)row * lda * 2 + (size_t)k0 * 2 + cb,
                   (char*)ldsA + it * 4096 + w * 1024);
      async_load16((const char*)Bt + (size_t)row * ldb * 2 + (size_t)k0 * 2 + cb,
                   (char*)ldsB + it * 4096 + w * 1024);
    }
    __syncthreads();
    short8 af[4], bfv[4];
#pragma unroll
    for (int mi = 0; mi < 4; ++mi)
      af[mi] = ld8(ldsA + (wm + mi * 16 + r) * 32 + kb);
#pragma unroll
    for (int ni = 0; ni < 4; ++ni)
      bfv[ni] = ld8(ldsB + (wn + ni * 16 + r) * 32 + kb);
#pragma unroll
    for (int mi = 0; mi < 4; ++mi)
#pragma unroll
      for (int ni = 0; ni < 4; ++ni)
        acc[mi][ni] = mfma16(af[mi], bfv[ni], acc[mi][ni]);
  }
}

// ---------------- fused QKV projection -----------------------------------
// K -> KF[h][t][kc][lane][8], V -> VF[h][t][c][dh][lane][8] (fragment-ready)
__global__ __launch_bounds__(256) void qkv_k(
    const bf16* __restrict__ q, const bf16* __restrict__ k, const bf16* __restrict__ v,
    const bf16* __restrict__ WT, const bf16* __restrict__ biasN,
    bf16* __restrict__ Q0, bf16* __restrict__ KF, bf16* __restrict__ VF) {
  __shared__ bf16 ldsA[128 * 32];
  __shared__ bf16 ldsB[128 * 32];
  int m0 = blockIdx.x * 128;
  int bc = blockIdx.y, sel = bc >> 2, n0 = (bc & 3) * 128;
  const bf16* A = sel == 0 ? q : sel == 1 ? k : v;
  const bf16* bias = biasN + sel * 512;
  const bf16* Bt = WT + (size_t)sel * 512 * 2048 + (size_t)n0 * 2048;
  f32x4 acc[4][4];
  f32x4 z = {0.f, 0.f, 0.f, 0.f};
#pragma unroll
  for (int mi = 0; mi < 4; ++mi)
#pragma unroll
    for (int ni = 0; ni < 4; ++ni) acc[mi][ni] = z;
  gemm128(A + (size_t)m0 * 2048, Bt, 2048, 2048, 2048, ldsA, ldsB, acc);
  const int t = threadIdx.x, w = t >> 6, lane = t & 63;
  const int wm = (w >> 1) * 64, wn = (w & 1) * 64;
#pragma unroll
  for (int mi = 0; mi < 4; ++mi)
#pragma unroll
    for (int ni = 0; ni < 4; ++ni)
#pragma unroll
      for (int i = 0; i < 4; ++i) {
        int row = m0 + wm + mi * 16 + ((lane >> 4) * 4 + i);
        int ch = n0 + wn + ni * 16 + (lane & 15);
        float val = acc[mi][ni][i] + __bfloat162float(bias[ch]);
        bf16 o = __float2bfloat16(val);
        if (sel == 0) {
          Q0[(size_t)row * 512 + ch] = o;
        } else if (sel == 1) {
          int h = ch >> 6, d = ch & 63;
          int tt = row >> 5, qq2 = row & 31;
          int kc = d >> 4, hp2 = (d >> 3) & 1, j = d & 7;
          KF[((((size_t)(h * 64 + tt) * 4 + kc) * 2 + hp2) * 32 + qq2) * 8 + j] = o;
        } else {
          int h = ch >> 6, d = ch & 63;
          int tt = row >> 5, c = (row >> 4) & 1, hp2 = (row >> 3) & 1, j = row & 7;
          int dh = d >> 5, qq2 = d & 31;
          VF[(((((size_t)(h * 64 + tt) * 2 + c) * 2 + dh) * 64) + hp2 * 32 + qq2) * 8 + j] = o;
        }
      }
}

// ---------------- per-kv-head compound transform (K=64 GEMM) --------------
// NOTE: output pre-scaled by 8 (softmax logit scale), exact in bf16.
__global__ __launch_bounds__(256) void gtrans_k(
    const bf16* __restrict__ Q0, const bf16* __restrict__ WGT,
    const bf16* __restrict__ bGN, bf16* __restrict__ QG) {
  __shared__ bf16 Wlds[256 * 64];
  __shared__ bf16 Qlds[64 * 64];
  int n0 = blockIdx.x * 64, h = blockIdx.y;
  int t = threadIdx.x, w = t >> 6, lane = t & 63;
  const char* wsrc = (const char*)(WGT + (size_t)h * 256 * 64);
#pragma unroll
  for (int it = 0; it < 8; ++it)
    async_load16(wsrc + it * 4096 + t * 16, (char*)Wlds + it * 4096 + w * 1024);
#pragma unroll
  for (int it = 0; it < 2; ++it) {
    int flat = it * 4096 + t * 16;
    int row = flat >> 7, cb = flat & 127;
    async_load16((const char*)Q0 + (size_t)(n0 + row) * 1024 + h * 128 + cb,
                 (char*)Qlds + it * 4096 + w * 1024);
  }
  __syncthreads();
  int r = lane & 15, kb = (lane >> 4) * 8;
  short8 af0 = ld8(Qlds + (w * 16 + r) * 64 + kb);
  short8 af1 = ld8(Qlds + (w * 16 + r) * 64 + 32 + kb);
#pragma unroll
  for (int ni = 0; ni < 16; ++ni) {
    f32x4 a = {0.f, 0.f, 0.f, 0.f};
    a = mfma16(af0, ld8(Wlds + (ni * 16 + r) * 64 + kb), a);
    a = mfma16(af1, ld8(Wlds + (ni * 16 + r) * 64 + 32 + kb), a);
    int e = ni * 16 + r;
    int g = e >> 6, d = e & 63;
    float bias = __bfloat162float(bGN[h * 256 + e]);
#pragma unroll
    for (int i = 0; i < 4; ++i) {
      int row = n0 + w * 16 + (lane >> 4) * 4 + i;
      QG[((size_t)(g * 8 + h) * 2048 + row) * 64 + d] =
          __float2bfloat16((a[i] + bias) * 8.0f);
    }
  }
}

// ---------------- flash attention: LDS-free, L2-direct, no barriers -------
// grid (16 qtiles of 128 [reversed], 32 heads); 4 indep waves x 32 q-rows.
__global__ __launch_bounds__(256) void attn_k(
    const bf16* __restrict__ QG, const bf16* __restrict__ KF,
    const bf16* __restrict__ VF, bf16* __restrict__ AO) {
  int q0 = (gridDim.x - 1 - blockIdx.x) * 128;
  int hh = blockIdx.y, g = hh >> 3, h = hh & 7;
  int t = threadIdx.x, w = t >> 6, lane = t & 63;
  int qq = lane & 31, hp = lane >> 5;
  const bf16* KFh = KF + (size_t)h * 131072;
  const bf16* VFh = VF + (size_t)h * 131072;
  const bf16* Qh = QG + (size_t)hh * 2048 * 64;
  int qrow = q0 + w * 32 + qq;
  int qmin = q0 + w * 32;

  short8 qf[4];
#pragma unroll
  for (int kc = 0; kc < 4; ++kc)
    qf[kc] = ld8(Qh + (size_t)qrow * 64 + kc * 16 + hp * 8);

  f32x16 acc[2];
#pragma unroll
  for (int i = 0; i < 16; ++i) { acc[0][i] = 0.f; acc[1][i] = 0.f; }
  float m_run = -1e30f, l_run = 0.f;

  short8 kf[4], knx[4];
#pragma unroll
  for (int kc = 0; kc < 4; ++kc)
    kf[kc] = ld8(KFh + ((size_t)kc * 64 + lane) * 8);

  int tlast = qmin >> 5;
  for (int t2 = 0; t2 <= tlast; ++t2) {
    bool hn = t2 < tlast;
    if (hn) {
#pragma unroll
      for (int kc = 0; kc < 4; ++kc)
        knx[kc] = ld8(KFh + (((size_t)(t2 + 1) * 4 + kc) * 64 + lane) * 8);
    }
    f32x16 sa;
#pragma unroll
    for (int i = 0; i < 16; ++i) sa[i] = 0.f;
#pragma unroll
    for (int kc = 0; kc < 4; ++kc) sa = mfma32(kf[kc], qf[kc], sa);
    if (t2 == tlast) {  // diagonal tile: mask s > qrow
#pragma unroll
      for (int rg = 0; rg < 16; ++rg) {
        int sr = t2 * 32 + (rg & 3) + 8 * (rg >> 2) + 4 * hp;
        if (sr > qrow) sa[rg] = -1e30f;
      }
    }
    float tmax = sa[0];
#pragma unroll
    for (int rg = 1; rg < 16; ++rg) tmax = fmaxf(tmax, sa[rg]);
    tmax = fmaxf(tmax, __shfl_xor(tmax, 32));
    if (!__all(tmax <= m_run + 8.0f)) {  // defer-max (T13)
      float mnew = fmaxf(m_run, tmax);
      float alpha = __expf(m_run - mnew);
      m_run = mnew;
      l_run *= alpha;
#pragma unroll
      for (int i = 0; i < 16; ++i) { acc[0][i] *= alpha; acc[1][i] *= alpha; }
    }
    float rs = 0.f;
#pragma unroll
    for (int rg = 0; rg < 16; ++rg) {
      float p = __expf(sa[rg] - m_run);
      sa[rg] = p;
      rs += p;
    }
    rs += __shfl_xor(rs, 32);
    l_run += rs;
    unsigned wpk[8];
#pragma unroll
    for (int rp = 0; rp < 8; ++rp) wpk[rp] = pk2(sa[2 * rp], sa[2 * rp + 1]);
#pragma unroll
    for (int c = 0; c < 2; ++c) {
      unsigned own0 = wpk[c * 4 + 0], own1 = wpk[c * 4 + 1];
      unsigned own2 = wpk[c * 4 + 2], own3 = wpk[c * 4 + 3];
      unsigned send0 = hp ? own0 : own2;
      unsigned send1 = hp ? own1 : own3;
      unsigned r0 = (unsigned)__shfl_xor((int)send0, 32);
      unsigned r1 = (unsigned)__shfl_xor((int)send1, 32);
      u32x4 pv;
      pv[0] = hp ? r0 : own0;
      pv[1] = hp ? r1 : own1;
      pv[2] = hp ? own2 : r0;
      pv[3] = hp ? own3 : r1;
      short8 pa = __builtin_bit_cast(short8, pv);
      short8 vf0 = ld8(VFh + ((((size_t)t2 * 2 + c) * 2 + 0) * 64 + lane) * 8);
      short8 vf1 = ld8(VFh + ((((size_t)t2 * 2 + c) * 2 + 1) * 64 + lane) * 8);
      acc[0] = mfma32(vf0, pa, acc[0]);  // d rows 0..31, q = lane&31
      acc[1] = mfma32(vf1, pa, acc[1]);  // d rows 32..63
    }
    if (hn) {
#pragma unroll
      for (int kc = 0; kc < 4; ++kc) kf[kc] = knx[kc];
    }
  }
  float rli = 1.0f / l_run;
  bf16* aob = AO + (size_t)qrow * 2048 + h * 256 + g * 64;
#pragma unroll
  for (int ds = 0; ds < 2; ++ds)
#pragma unroll
    for (int rq = 0; rq < 4; ++rq) {
      s16x4 o4;
#pragma unroll
      for (int i = 0; i < 4; ++i)
        o4[i] = __builtin_bit_cast(short, __float2bfloat16(acc[ds][rq * 4 + i] * rli));
      int d0 = ds * 32 + 8 * rq + 4 * hp;
      *(s16x4*)(aob + d0) = o4;
    }
}

// ---------------- output projection (dtype-flexible store) ----------------
__global__ __launch_bounds__(256) void outproj_k(
    const bf16* __restrict__ AO, const bf16* __restrict__ WfcT,
    const bf16* __restrict__ bfcN, void* __restrict__ outv,
    const int* __restrict__ flag) {
  __shared__ bf16 ldsA[128 * 32];
  __shared__ bf16 ldsB[128 * 32];
  int f = *flag;
  int m0 = blockIdx.x * 128, n0 = blockIdx.y * 128;
  f32x4 acc[4][4];
  f32x4 z = {0.f, 0.f, 0.f, 0.f};
#pragma unroll
  for (int mi = 0; mi < 4; ++mi)
#pragma unroll
    for (int ni = 0; ni < 4; ++ni) acc[mi][ni] = z;
  gemm128(AO + (size_t)m0 * 2048, WfcT + (size_t)n0 * 2048, 2048, 2048, 2048,
          ldsA, ldsB, acc);
  const int t = threadIdx.x, w = t >> 6, lane = t & 63;
  const int wm = (w >> 1) * 64, wn = (w & 1) * 64;
#pragma unroll
  for (int mi = 0; mi < 4; ++mi)
#pragma unroll
    for (int ni = 0; ni < 4; ++ni)
#pragma unroll
      for (int i = 0; i < 4; ++i) {
        int row = m0 + wm + mi * 16 + ((lane >> 4) * 4 + i);
        int ch = n0 + wn + ni * 16 + (lane & 15);
        float val = acc[mi][ni][i] + __bfloat162float(bfcN[ch]);
        size_t idx = (size_t)row * 2048 + ch;
        if (f) ((float*)outv)[idx] = val;
        else   ((bf16*)outv)[idx] = __float2bfloat16(val);
      }
}

extern "C" void kernel_launch(void* const* d_in, const int* in_sizes, int n_in,
                              void* d_out, int out_size, void* d_ws, size_t ws_size,
                              hipStream_t stream) {
  const void* q   = d_in[0];
  const void* k   = d_in[1];
  const void* v   = d_in[2];
  const void* Wq  = d_in[3];
  const void* bq  = d_in[4];
  const void* Wk  = d_in[5];
  const void* bk  = d_in[6];
  const void* Wv  = d_in[7];
  const void* bv  = d_in[8];
  const void* WG  = d_in[9];
  const void* bG  = d_in[10];
  const void* Wfc = d_in[11];
  const void* bfc = d_in[12];

  bf16* ws = (bf16*)d_ws;
  int* flag = (int*)d_ws;           // elems [0,32)
  bf16* biasN = ws + 32;
  bf16* WT    = ws + 6144;          // 3*512*2048
  bf16* WGT   = ws + 3151872;       // 8*256*64
  bf16* Q0    = ws + 3282944;       // 2048*512
  bf16* KF    = ws + 4331520;       // 8*64*4*2*32*8 = 1M (fragment-ready K)
  bf16* VF    = ws + 5380096;       // 8*64*2*2*64*8 = 1M (fragment-ready V)
  bf16* R1    = ws + 6428672;       // 4M: qn, then QG
  bf16* R2    = ws + 10622976;      // 4M: kn, then AO
  bf16* R3    = ws + 14817280;      // 4M: vn, then WfcT
  bf16* qn = R1; bf16* QG = R1;
  bf16* kn = R2; bf16* AO = R2;
  bf16* vn = R3; bf16* WfcT = R3;
  bf16* bGN = biasN + 1536, *bfcN = biasN + 3584;

  detect_k<<<1, 64, 0, stream>>>(q, flag);
  convert3_k<<<dim3(1024, 1, 3), 256, 0, stream>>>(q, k, v, qn, kn, vn, 4194304, flag);
  convert5_k<<<1, 256, 0, stream>>>(bq, bk, bv, bG, bfc, biasN, flag);

  dim3 b32(32, 32, 1);
  transpose_w3_k<<<dim3(16, 64, 3), b32, 0, stream>>>(Wq, Wk, Wv, WT, flag);
  transpose_cvt_k<<<dim3(8, 2, 8), b32, 0, stream>>>(WG, WGT, 64, 256, flag);

  qkv_k<<<dim3(16, 12, 1), 256, 0, stream>>>(qn, kn, vn, WT, biasN, Q0, KF, VF);
  gtrans_k<<<dim3(32, 8, 1), 256, 0, stream>>>(Q0, WGT, bGN, QG);
  attn_k<<<dim3(16, 32, 1), 256, 0, stream>>>(QG, KF, VF, AO);
  transpose_cvt_k<<<dim3(64, 64, 1), b32, 0, stream>>>(Wfc, WfcT, 2048, 2048, flag);
  outproj_k<<<dim3(16, 16, 1), 256, 0, stream>>>(AO, WfcT, bfcN, d_out, flag);
}